// Round 6
// baseline (1489.582 us; speedup 1.0000x reference)
//
#include <hip/hip_runtime.h>

typedef int v4i __attribute__((ext_vector_type(4)));

static constexpr int K_DIM = 4096;
static constexpr int BM = 256, BN = 256, BK = 128;
static constexpr int NT = K_DIM / BK;                 // 32 K-tiles

// ---------------- per-token dynamic quantization ----------------
__global__ __launch_bounds__(256) void quant_kernel(const float* __restrict__ x,
                                                    signed char* __restrict__ xq,
                                                    float* __restrict__ xs) {
    const int token = blockIdx.x;
    const float4* row = (const float4*)(x + (size_t)token * K_DIM);
    const int t = threadIdx.x;
    float4 v[4];
    float m = 0.f;
#pragma unroll
    for (int i = 0; i < 4; ++i) {
        v[i] = row[t * 4 + i];
        m = fmaxf(m, fabsf(v[i].x));
        m = fmaxf(m, fabsf(v[i].y));
        m = fmaxf(m, fabsf(v[i].z));
        m = fmaxf(m, fabsf(v[i].w));
    }
#pragma unroll
    for (int d = 32; d > 0; d >>= 1) m = fmaxf(m, __shfl_xor(m, d));
    __shared__ float red[4];
    if ((t & 63) == 0) red[t >> 6] = m;
    __syncthreads();
    const float am = fmaxf(fmaxf(red[0], red[1]), fmaxf(red[2], red[3]));
    const float s = fmaxf(am, 1e-8f) * (1.0f / 127.0f);
    const float inv = 127.0f / fmaxf(am, 1e-8f);

    int pk[4];
#pragma unroll
    for (int i = 0; i < 4; ++i) {
        int q0 = (int)fminf(127.f, fmaxf(-127.f, rintf(v[i].x * inv)));
        int q1 = (int)fminf(127.f, fmaxf(-127.f, rintf(v[i].y * inv)));
        int q2 = (int)fminf(127.f, fmaxf(-127.f, rintf(v[i].z * inv)));
        int q3 = (int)fminf(127.f, fmaxf(-127.f, rintf(v[i].w * inv)));
        pk[i] = (q0 & 255) | ((q1 & 255) << 8) | ((q2 & 255) << 16) | (q3 << 24);
    }
    ((int4*)(xq + (size_t)token * K_DIM))[t] = make_int4(pk[0], pk[1], pk[2], pk[3]);
    if (t == 0) xs[token] = s;
}

// ---------------- weight repack: int32 -> packed int8 ----------------
__global__ __launch_bounds__(256) void repack_kernel(const int* __restrict__ w32,
                                                     int4* __restrict__ w8,
                                                     int n16) {
    const int idx = blockIdx.x * 256 + threadIdx.x;
    if (idx >= n16) return;
    const int4* src = (const int4*)w32 + (size_t)idx * 4;
    int4 a = src[0], b = src[1], c = src[2], d = src[3];
    int p0 = (a.x & 255) | ((a.y & 255) << 8) | ((a.z & 255) << 16) | (a.w << 24);
    int p1 = (b.x & 255) | ((b.y & 255) << 8) | ((b.z & 255) << 16) | (b.w << 24);
    int p2 = (c.x & 255) | ((c.y & 255) << 8) | ((c.z & 255) << 16) | (c.w << 24);
    int p3 = (d.x & 255) | ((d.y & 255) << 8) | ((d.z & 255) << 16) | (d.w << 24);
    w8[idx] = make_int4(p0, p1, p2, p3);
}

// ---- frag reads: zero-conflict pattern (128-B rows, col XOR (lane&7)<<4) ----
#define RDAL(BUF, CX)                                                                 \
    _Pragma("unroll") for (int mi = 0; mi < 4; ++mi)                                  \
        al[mi] = *(const v4i*)&sA[BUF][roffA + mi * 2048 + (CX)];
#define RDAH(BUF, CX)                                                                 \
    _Pragma("unroll") for (int mi = 0; mi < 4; ++mi)                                  \
        ah[mi] = *(const v4i*)&sA[BUF][roffA + 8192 + mi * 2048 + (CX)];
#define RDB0(BUF, CX)                                                                 \
    _Pragma("unroll") for (int ni = 0; ni < 2; ++ni)                                  \
        b0[ni] = *(const v4i*)&sB[BUF][roffB + ni * 2048 + (CX)];
#define RDB1(BUF, CX)                                                                 \
    _Pragma("unroll") for (int ni = 0; ni < 2; ++ni)                                  \
        b1[ni] = *(const v4i*)&sB[BUF][roffB + 16384 + ni * 2048 + (CX)];
#define MML(NH, BF)                                                                   \
    _Pragma("unroll") for (int mi = 0; mi < 4; ++mi)                                  \
    _Pragma("unroll") for (int ni = 0; ni < 2; ++ni)                                  \
        acc[mi][(NH) * 2 + ni] = __builtin_amdgcn_mfma_i32_16x16x64_i8(               \
            al[mi], BF[ni], acc[mi][(NH) * 2 + ni], 0, 0, 0);
#define MMH(NH, BF)                                                                   \
    _Pragma("unroll") for (int mi = 0; mi < 4; ++mi)                                  \
    _Pragma("unroll") for (int ni = 0; ni < 2; ++ni)                                  \
        acc[4 + mi][(NH) * 2 + ni] = __builtin_amdgcn_mfma_i32_16x16x64_i8(           \
            ah[mi], BF[ni], acc[4 + mi][(NH) * 2 + ni], 0, 0, 0);
#define SINK(F) asm volatile("" :: "v"(F[0]), "v"(F[1]), "v"(F[2]), "v"(F[3]))
#define SINKAL { SINK(al[0]); SINK(al[1]); SINK(al[2]); SINK(al[3]); }
#define SINKAH { SINK(ah[0]); SINK(ah[1]); SINK(ah[2]); SINK(ah[3]); }
#define SINKB  { SINK(b0[0]); SINK(b0[1]); SINK(b1[0]); SINK(b1[1]); }

// MODE: 0=full(real out) 1=no-stage 2=no-dsread 3=no-mfma 4=mfma-only
template<int MODE>
__global__ __launch_bounds__(512, 2) void gemm_kernel(const signed char* __restrict__ xq,
                                                      const signed char* __restrict__ w8,
                                                      const float* __restrict__ xs,
                                                      const float* __restrict__ scale,
                                                      const float* __restrict__ bias,
                                                      float* __restrict__ out,
                                                      int N) {
    constexpr bool ST = (MODE == 0 || MODE == 2 || MODE == 3);
    constexpr bool RD = (MODE == 0 || MODE == 1 || MODE == 3);
    constexpr bool MM = (MODE == 0 || MODE == 1 || MODE == 2 || MODE == 4);

    __shared__ __align__(16) signed char sA[2][BM * BK];   // 2 x 32 KB
    __shared__ __align__(16) signed char sB[2][BN * BK];   // 2 x 32 KB

    const int tid = threadIdx.x;
    const int lane = tid & 63;
    const int wid = tid >> 6;          // 8 waves: 2(M) x 4(N)
    const int wm = wid >> 2;
    const int wn = wid & 3;

    const int nwg = gridDim.x * gridDim.y;
    int flat = blockIdx.y * gridDim.x + blockIdx.x;
    if ((nwg & 7) == 0) flat = (flat & 7) * (nwg >> 3) + (flat >> 3);
    const int by = flat % gridDim.y;
    const int bx = flat / gridDim.y;
    const int m0 = by * BM;
    const int n0 = bx * BN;

    v4i acc[8][4];
    const v4i vzero = {0, 0, 0, 0};
#pragma unroll
    for (int i = 0; i < 8; ++i)
#pragma unroll
        for (int j = 0; j < 4; ++j) acc[i][j] = vzero;

    const int t8 = tid >> 3;
    const int sswz = (((tid & 7) ^ (t8 & 7)) << 4);
    const signed char* srcA = xq + ((size_t)m0 + t8) * K_DIM + sswz;
    const int gBrow = ((t8 >> 5) << 6) + (t8 & 31);
    const signed char* srcB = w8 + ((size_t)n0 + gBrow) * K_DIM + sswz;

    auto stage6 = [&](int buf, int kb) {
        __builtin_amdgcn_global_load_lds((const __attribute__((address_space(1))) void*)(srcA + kb),
            (__attribute__((address_space(3))) void*)&sA[buf][0 * 8192 + wid * 1024], 16, 0, 0);
        __builtin_amdgcn_global_load_lds((const __attribute__((address_space(1))) void*)(srcA + 128 * K_DIM + kb),
            (__attribute__((address_space(3))) void*)&sA[buf][2 * 8192 + wid * 1024], 16, 0, 0);
        __builtin_amdgcn_global_load_lds((const __attribute__((address_space(1))) void*)(srcB + kb),
            (__attribute__((address_space(3))) void*)&sB[buf][0 * 8192 + wid * 1024], 16, 0, 0);
        __builtin_amdgcn_global_load_lds((const __attribute__((address_space(1))) void*)(srcB + 128 * K_DIM + kb),
            (__attribute__((address_space(3))) void*)&sB[buf][1 * 8192 + wid * 1024], 16, 0, 0);
        __builtin_amdgcn_global_load_lds((const __attribute__((address_space(1))) void*)(srcB + 32 * K_DIM + kb),
            (__attribute__((address_space(3))) void*)&sB[buf][2 * 8192 + wid * 1024], 16, 0, 0);
        __builtin_amdgcn_global_load_lds((const __attribute__((address_space(1))) void*)(srcB + 160 * K_DIM + kb),
            (__attribute__((address_space(3))) void*)&sB[buf][3 * 8192 + wid * 1024], 16, 0, 0);
    };
    auto stage2 = [&](int buf, int kb) {
        __builtin_amdgcn_global_load_lds((const __attribute__((address_space(1))) void*)(srcA + 64 * K_DIM + kb),
            (__attribute__((address_space(3))) void*)&sA[buf][1 * 8192 + wid * 1024], 16, 0, 0);
        __builtin_amdgcn_global_load_lds((const __attribute__((address_space(1))) void*)(srcA + 192 * K_DIM + kb),
            (__attribute__((address_space(3))) void*)&sA[buf][3 * 8192 + wid * 1024], 16, 0, 0);
    };

    const int colx0 = ((lane >> 4) << 4) ^ ((lane & 7) << 4);
    const int colx1 = colx0 ^ 64;
    const int roffA = (wm * 128 + (lane & 15)) * BK;
    const int roffB = (wn * 32 + (lane & 15)) * BK;

    v4i al[4], ah[4], b0[2], b1[2];
    if constexpr (!RD) {   // register-constant operands for MFMA-with-no-dsread modes
#pragma unroll
        for (int i = 0; i < 4; ++i) {
            al[i] = (v4i){tid, i, tid ^ i, 7};
            ah[i] = (v4i){i, tid, 3, tid + i};
        }
#pragma unroll
        for (int i = 0; i < 2; ++i) {
            b0[i] = (v4i){tid + i, 1, 2, 3};
            b1[i] = (v4i){5, tid, i, 9};
        }
    }

    if constexpr (MODE == 4) {
        // pure matrix-pipe probe: 64 MFMA per K-tile, no memory, no barriers
        for (int kt = 0; kt < NT; ++kt) {
            MML(0, b0); MML(1, b1);
            MMH(0, b0); MMH(1, b1);
        }
    } else {
        if constexpr (ST) {
            stage6(0, 0);
            stage2(0, 0);
            asm volatile("s_waitcnt vmcnt(2)" ::: "memory");
        }
        __builtin_amdgcn_s_barrier();

        for (int kt = 0; kt < NT - 1; ++kt) {
            const int db = kt & 1;
            const int kb = (kt + 1) * BK;

            // P0
            if constexpr (!ST) asm volatile("" ::: "memory");   // block LICM of ds_reads
            if constexpr (RD) { RDAL(db, colx0); RDB0(db, colx0); RDB1(db, colx0); }
            if constexpr (ST) {
                stage6(db ^ 1, kb);
                asm volatile("s_waitcnt vmcnt(6)" ::: "memory");
            }
            __builtin_amdgcn_s_barrier();
            asm volatile("s_waitcnt lgkmcnt(0)" ::: "memory");
            if constexpr (MM) {
                __builtin_amdgcn_s_setprio(1);
                MML(0, b0); MML(1, b1);
                __builtin_amdgcn_s_setprio(0);
            } else { SINKAL; SINKB; }
            __builtin_amdgcn_s_barrier();

            // P1
            if constexpr (!ST) asm volatile("" ::: "memory");
            if constexpr (RD) { RDAH(db, colx0); }
            if constexpr (ST) stage2(db ^ 1, kb);
            __builtin_amdgcn_s_barrier();
            asm volatile("s_waitcnt lgkmcnt(0)" ::: "memory");
            if constexpr (MM) {
                __builtin_amdgcn_s_setprio(1);
                MMH(0, b0); MMH(1, b1);
                __builtin_amdgcn_s_setprio(0);
            } else { SINKAH; }
            __builtin_amdgcn_s_barrier();

            // P2
            if constexpr (!ST) asm volatile("" ::: "memory");
            if constexpr (RD) { RDAL(db, colx1); RDB0(db, colx1); RDB1(db, colx1); }
            __builtin_amdgcn_s_barrier();
            asm volatile("s_waitcnt lgkmcnt(0)" ::: "memory");
            if constexpr (MM) {
                __builtin_amdgcn_s_setprio(1);
                MML(0, b0); MML(1, b1);
                __builtin_amdgcn_s_setprio(0);
            } else { SINKAL; SINKB; }
            __builtin_amdgcn_s_barrier();

            // P3
            if constexpr (!ST) asm volatile("" ::: "memory");
            if constexpr (RD) { RDAH(db, colx1); }
            if constexpr (ST) asm volatile("s_waitcnt vmcnt(2)" ::: "memory");
            __builtin_amdgcn_s_barrier();
            asm volatile("s_waitcnt lgkmcnt(0)" ::: "memory");
            if constexpr (MM) {
                __builtin_amdgcn_s_setprio(1);
                MMH(0, b0); MMH(1, b1);
                __builtin_amdgcn_s_setprio(0);
            } else { SINKAH; }
            __builtin_amdgcn_s_barrier();
        }

        // last K-tile
        {
            const int db = (NT - 1) & 1;
            if constexpr (!ST) asm volatile("" ::: "memory");
            if constexpr (RD) { RDAL(db, colx0); RDB0(db, colx0); RDB1(db, colx0); }
            if constexpr (ST) asm volatile("s_waitcnt vmcnt(0)" ::: "memory");
            __builtin_amdgcn_s_barrier();
            asm volatile("s_waitcnt lgkmcnt(0)" ::: "memory");
            if constexpr (MM) { MML(0, b0); MML(1, b1); } else { SINKAL; SINKB; }
            if constexpr (RD) { RDAH(db, colx0); }
            asm volatile("s_waitcnt lgkmcnt(0)" ::: "memory");
            if constexpr (MM) { MMH(0, b0); MMH(1, b1); } else { SINKAH; }
            if constexpr (RD) { RDAL(db, colx1); RDB0(db, colx1); RDB1(db, colx1); }
            asm volatile("s_waitcnt lgkmcnt(0)" ::: "memory");
            if constexpr (MM) { MML(0, b0); MML(1, b1); } else { SINKAL; SINKB; }
            if constexpr (RD) { RDAH(db, colx1); }
            asm volatile("s_waitcnt lgkmcnt(0)" ::: "memory");
            if constexpr (MM) { MMH(0, b0); MMH(1, b1); } else { SINKAH; }
        }
    }

    if constexpr (MODE == 0) {
        const int mrow0 = m0 + wm * 128 + ((lane >> 4) << 2);
        const int ncol0 = n0 + wn * 64 + (lane & 15);
        float xsv[8][4];
#pragma unroll
        for (int mi = 0; mi < 8; ++mi)
#pragma unroll
            for (int r = 0; r < 4; ++r) xsv[mi][r] = xs[mrow0 + mi * 16 + r];

#pragma unroll
        for (int ni = 0; ni < 4; ++ni) {
            const int n = ncol0 + ni * 16;
            const float sc = scale[n];
            const float bs = bias[n];
#pragma unroll
            for (int mi = 0; mi < 8; ++mi) {
#pragma unroll
                for (int r = 0; r < 4; ++r) {
                    const int m = mrow0 + mi * 16 + r;
                    out[(size_t)m * N + n] = (float)acc[mi][ni][r] * xsv[mi][r] * sc + bs;
                }
            }
        }
    } else {
        int cs = 0;
#pragma unroll
        for (int i = 0; i < 8; ++i)
#pragma unroll
            for (int j = 0; j < 4; ++j)
#pragma unroll
                for (int r = 0; r < 4; ++r) cs += acc[i][j][r];
        const int bid = blockIdx.y * gridDim.x + blockIdx.x;
        out[(size_t)bid * 512 + tid] = (float)cs;   // scratch; overwritten by MODE 0
    }
}

extern "C" void kernel_launch(void* const* d_in, const int* in_sizes, int n_in,
                              void* d_out, int out_size, void* d_ws, size_t ws_size,
                              hipStream_t stream) {
    const float* x     = (const float*)d_in[0];
    const int*   w32   = (const int*)d_in[1];
    const float* scale = (const float*)d_in[2];
    const float* bias  = (const float*)d_in[3];
    float* out = (float*)d_out;

    const int M = in_sizes[0] / K_DIM;   // 8192
    const int N = in_sizes[2];           // 11008

    char* ws = (char*)d_ws;
    signed char* xq = (signed char*)ws;
    float* xs = (float*)(ws + (size_t)M * K_DIM);
    signed char* w8 = (signed char*)(ws + (size_t)M * K_DIM + (size_t)M * sizeof(float));

    quant_kernel<<<M, 256, 0, stream>>>(x, xq, xs);

    const int n16 = (N * K_DIM) / 16;
    repack_kernel<<<(n16 + 255) / 256, 256, 0, stream>>>(w32, (int4*)w8, n16);

    const dim3 grid(N / BN, M / BM);
    // ---- ablation probes (write checksums into d_out; real kernel runs last) ----
    gemm_kernel<1><<<grid, 512, 0, stream>>>(xq, w8, xs, scale, bias, out, N);  // no stage
    gemm_kernel<2><<<grid, 512, 0, stream>>>(xq, w8, xs, scale, bias, out, N);  // no dsread
    gemm_kernel<3><<<grid, 512, 0, stream>>>(xq, w8, xs, scale, bias, out, N);  // no mfma
    gemm_kernel<4><<<grid, 512, 0, stream>>>(xq, w8, xs, scale, bias, out, N);  // mfma only
    // ---- real kernel (final, correct output) ----
    gemm_kernel<0><<<grid, 512, 0, stream>>>(xq, w8, xs, scale, bias, out, N);
}

// Round 7
// 571.938 us; speedup vs baseline: 2.6044x; 2.6044x over previous
//
#include <hip/hip_runtime.h>

typedef int v4i __attribute__((ext_vector_type(4)));

static constexpr int K_DIM = 4096;
static constexpr int BM = 128, BN = 256, BK = 64;
static constexpr int NT2 = K_DIM / BK;                // 64 K-tiles

// ---------------- per-token dynamic quantization ----------------
__global__ __launch_bounds__(256) void quant_kernel(const float* __restrict__ x,
                                                    signed char* __restrict__ xq,
                                                    float* __restrict__ xs) {
    const int token = blockIdx.x;
    const float4* row = (const float4*)(x + (size_t)token * K_DIM);
    const int t = threadIdx.x;
    float4 v[4];
    float m = 0.f;
#pragma unroll
    for (int i = 0; i < 4; ++i) {
        v[i] = row[t * 4 + i];
        m = fmaxf(m, fabsf(v[i].x));
        m = fmaxf(m, fabsf(v[i].y));
        m = fmaxf(m, fabsf(v[i].z));
        m = fmaxf(m, fabsf(v[i].w));
    }
#pragma unroll
    for (int d = 32; d > 0; d >>= 1) m = fmaxf(m, __shfl_xor(m, d));
    __shared__ float red[4];
    if ((t & 63) == 0) red[t >> 6] = m;
    __syncthreads();
    const float am = fmaxf(fmaxf(red[0], red[1]), fmaxf(red[2], red[3]));
    const float s = fmaxf(am, 1e-8f) * (1.0f / 127.0f);
    const float inv = 127.0f / fmaxf(am, 1e-8f);

    int pk[4];
#pragma unroll
    for (int i = 0; i < 4; ++i) {
        int q0 = (int)fminf(127.f, fmaxf(-127.f, rintf(v[i].x * inv)));
        int q1 = (int)fminf(127.f, fmaxf(-127.f, rintf(v[i].y * inv)));
        int q2 = (int)fminf(127.f, fmaxf(-127.f, rintf(v[i].z * inv)));
        int q3 = (int)fminf(127.f, fmaxf(-127.f, rintf(v[i].w * inv)));
        pk[i] = (q0 & 255) | ((q1 & 255) << 8) | ((q2 & 255) << 16) | (q3 << 24);
    }
    ((int4*)(xq + (size_t)token * K_DIM))[t] = make_int4(pk[0], pk[1], pk[2], pk[3]);
    if (t == 0) xs[token] = s;
}

// ---------------- weight repack: int32 -> packed int8 ----------------
__global__ __launch_bounds__(256) void repack_kernel(const int* __restrict__ w32,
                                                     int4* __restrict__ w8,
                                                     int n16) {
    const int idx = blockIdx.x * 256 + threadIdx.x;
    if (idx >= n16) return;
    const int4* src = (const int4*)w32 + (size_t)idx * 4;
    int4 a = src[0], b = src[1], c = src[2], d = src[3];
    int p0 = (a.x & 255) | ((a.y & 255) << 8) | ((a.z & 255) << 16) | (a.w << 24);
    int p1 = (b.x & 255) | ((b.y & 255) << 8) | ((b.z & 255) << 16) | (b.w << 24);
    int p2 = (c.x & 255) | ((c.y & 255) << 8) | ((c.z & 255) << 16) | (c.w << 24);
    int p3 = (d.x & 255) | ((d.y & 255) << 8) | ((d.z & 255) << 16) | (d.w << 24);
    w8[idx] = make_int4(p0, p1, p2, p3);
}

// ---- int8 MFMA GEMM: 128x256 tile, BK=64 packed into 128-B LDS rows,
// ---- double-buffered 48 KB LDS -> 2 blocks/CU, counted-vmcnt pipeline ----
// Packing: LDS row r (128 B) holds K-chunk of matrix-row r (slots 0-3) and
// matrix-row r+HALF (slots 4-7); slot s stored at phys slot s ^ (r&7).
// Physical read/write pattern is byte-identical to the R4-measured
// zero-conflict layout.
__global__ __launch_bounds__(512, 4) void gemm_kernel(const signed char* __restrict__ xq,
                                                      const signed char* __restrict__ w8,
                                                      const float* __restrict__ xs,
                                                      const float* __restrict__ scale,
                                                      const float* __restrict__ bias,
                                                      float* __restrict__ out,
                                                      int N) {
    __shared__ __align__(16) signed char sA[2][64 * 128];    // 8 KB per buf
    __shared__ __align__(16) signed char sB[2][128 * 128];   // 16 KB per buf

    const int tid = threadIdx.x;
    const int lane = tid & 63;
    const int wid = tid >> 6;          // 8 waves: 2(M) x 4(N)
    const int wm = wid >> 2;
    const int wn = wid & 3;

    // T1: XCD-aware bijective swizzle (grid = 43 x 64 = 2752, divisible by 8)
    const int nwg = gridDim.x * gridDim.y;
    int flat = blockIdx.y * gridDim.x + blockIdx.x;
    if ((nwg & 7) == 0) flat = (flat & 7) * (nwg >> 3) + (flat >> 3);
    const int by = flat % gridDim.y;          // M fast -> B panel reused within chunk
    const int bx = flat / gridDim.y;
    const int m0 = by * BM;
    const int n0 = bx * BN;

    v4i acc[4][4];
    const v4i vzero = {0, 0, 0, 0};
#pragma unroll
    for (int i = 0; i < 4; ++i)
#pragma unroll
        for (int j = 0; j < 4; ++j) acc[i][j] = vzero;

    // ---- staging sources (per-thread constant; LDS dest linear) ----
    // thread -> LDS byte tid*16: row = tid>>3 (0..63), phys slot = tid&7
    // logical slot s = phys ^ (row&7); s>>2 selects packed row-half, s&3 the k-quarter
    const int srow = tid >> 3;
    const int s = (tid & 7) ^ (srow & 7);
    const signed char* srcA = xq + ((size_t)m0 + srow + (s >> 2) * 64) * K_DIM + (s & 3) * 16;
    const signed char* srcB = w8 + ((size_t)n0 + srow + (s >> 2) * 128) * K_DIM + (s & 3) * 16;

    auto stage = [&](int buf, int kb) {   // 3 issues: A(8KB), B lo(8KB), B hi(8KB)
        __builtin_amdgcn_global_load_lds(
            (const __attribute__((address_space(1))) void*)(srcA + kb),
            (__attribute__((address_space(3))) void*)&sA[buf][wid * 1024], 16, 0, 0);
        __builtin_amdgcn_global_load_lds(
            (const __attribute__((address_space(1))) void*)(srcB + kb),
            (__attribute__((address_space(3))) void*)&sB[buf][wid * 1024], 16, 0, 0);
        __builtin_amdgcn_global_load_lds(
            (const __attribute__((address_space(1))) void*)(srcB + (size_t)64 * K_DIM + kb),
            (__attribute__((address_space(3))) void*)&sB[buf][8192 + wid * 1024], 16, 0, 0);
    };

    // ---- read-side per-lane constants (verified zero-conflict pattern) ----
    const int colA = ((wm * 4 + (lane >> 4)) ^ (lane & 7)) << 4;            // wm selects packed half
    const int colB = (((wn >> 1) * 4 + (lane >> 4)) ^ (lane & 7)) << 4;     // wn>>1 selects packed half
    const int rowA = (lane & 15) * 128;                                     // + mi*2048
    const int rowB = ((wn & 1) * 64 + (lane & 15)) * 128;                   // + ni*2048

    // prologue: 2-deep prefetch
    stage(0, 0);
    stage(1, BK);
    asm volatile("s_waitcnt vmcnt(3)" ::: "memory");   // buf0's 3 issues complete
    __builtin_amdgcn_s_barrier();

    for (int kt = 0; kt < NT2; ++kt) {
        const int cur = kt & 1;
        v4i a[4], b[4];
#pragma unroll
        for (int mi = 0; mi < 4; ++mi)
            a[mi] = *(const v4i*)&sA[cur][rowA + mi * 2048 + colA];
#pragma unroll
        for (int ni = 0; ni < 4; ++ni)
            b[ni] = *(const v4i*)&sB[cur][rowB + ni * 2048 + colB];

        __builtin_amdgcn_s_setprio(1);
#pragma unroll
        for (int mi = 0; mi < 4; ++mi)
#pragma unroll
            for (int ni = 0; ni < 4; ++ni)
                acc[mi][ni] = __builtin_amdgcn_mfma_i32_16x16x64_i8(a[mi], b[ni], acc[mi][ni], 0, 0, 0);
        __builtin_amdgcn_s_setprio(0);

        __builtin_amdgcn_s_barrier();          // all waves done reading buf[cur]
        asm volatile("" ::: "memory");
        if (kt + 2 < NT2) {
            stage(cur, (kt + 2) * BK);         // overwrite cur with tile kt+2
            asm volatile("s_waitcnt vmcnt(3)" ::: "memory");   // tile kt+1 landed
        } else if (kt + 1 < NT2) {
            asm volatile("s_waitcnt vmcnt(0)" ::: "memory");   // final tile landed
        }
        __builtin_amdgcn_s_barrier();          // publish buf[cur^1]
    }

    // ---- output epilogue: D reg r of lane l -> row (l>>4)*4+r, col l&15 per frag
    const int mrow0 = m0 + wm * 64 + ((lane >> 4) << 2);
    const int ncol0 = n0 + wn * 64 + (lane & 15);
    float xsv[4][4];
#pragma unroll
    for (int mi = 0; mi < 4; ++mi)
#pragma unroll
        for (int r = 0; r < 4; ++r) xsv[mi][r] = xs[mrow0 + mi * 16 + r];

#pragma unroll
    for (int ni = 0; ni < 4; ++ni) {
        const int n = ncol0 + ni * 16;
        const float sc = scale[n];
        const float bs = bias[n];
#pragma unroll
        for (int mi = 0; mi < 4; ++mi) {
#pragma unroll
            for (int r = 0; r < 4; ++r) {
                const int m = mrow0 + mi * 16 + r;
                out[(size_t)m * N + n] = (float)acc[mi][ni][r] * xsv[mi][r] * sc + bs;
            }
        }
    }
}

extern "C" void kernel_launch(void* const* d_in, const int* in_sizes, int n_in,
                              void* d_out, int out_size, void* d_ws, size_t ws_size,
                              hipStream_t stream) {
    const float* x     = (const float*)d_in[0];
    const int*   w32   = (const int*)d_in[1];
    const float* scale = (const float*)d_in[2];
    const float* bias  = (const float*)d_in[3];
    float* out = (float*)d_out;

    const int M = in_sizes[0] / K_DIM;   // 8192
    const int N = in_sizes[2];           // 11008

    char* ws = (char*)d_ws;
    signed char* xq = (signed char*)ws;                                  // M*K
    float* xs = (float*)(ws + (size_t)M * K_DIM);                        // M floats
    signed char* w8 = (signed char*)(ws + (size_t)M * K_DIM + (size_t)M * sizeof(float));  // N*K

    quant_kernel<<<M, 256, 0, stream>>>(x, xq, xs);

    const int n16 = (N * K_DIM) / 16;
    repack_kernel<<<(n16 + 255) / 256, 256, 0, stream>>>(w32, (int4*)w8, n16);

    gemm_kernel<<<dim3(N / BN, M / BM), 512, 0, stream>>>(xq, w8, xs, scale, bias, out, N);
}